// Round 3
// baseline (64762.653 us; speedup 1.0000x reference)
//
#include <hip/hip_runtime.h>
#include <stdint.h>

#define M_SEQ 8192
#define N_DIM 2048
#define N3    (3 * N_DIM)   // 6144

typedef short bf16x8 __attribute__((ext_vector_type(8)));   // 8 bf16 in 4 VGPRs
typedef float f32x4  __attribute__((ext_vector_type(4)));
typedef unsigned short u16;
typedef unsigned long long u64;

// fp32 -> bf16, round-to-nearest-even
__device__ __forceinline__ u16 f2bf(float f) {
    unsigned int u = __builtin_bit_cast(unsigned int, f);
    u = (u + 0x7fffu + ((u >> 16) & 1u)) >> 16;
    return (u16)u;
}
__device__ __forceinline__ float bf2f(u16 v) {
    return __builtin_bit_cast(float, (unsigned int)v << 16);
}

// ---------------------------------------------------------------------------
// in [R][C] fp32 -> out [C][R] bf16  (tiled transpose)
__global__ void k_tr_bf16(const float* __restrict__ in, u16* __restrict__ out, int R, int C) {
    __shared__ float tile[32][33];
    const int tx = threadIdx.x & 31, ty = threadIdx.x >> 5;
    const int c = blockIdx.x * 32 + tx;
#pragma unroll
    for (int k = 0; k < 4; ++k)
        tile[ty + k * 8][tx] = in[(size_t)(blockIdx.y * 32 + ty + k * 8) * C + c];
    __syncthreads();
#pragma unroll
    for (int k = 0; k < 4; ++k)
        out[(size_t)(blockIdx.x * 32 + ty + k * 8) * R + blockIdx.y * 32 + tx] =
            f2bf(tile[tx][ty + k * 8]);
}

// in [R][C] fp32 -> out [C][R] fp32
__global__ void k_tr_f32(const float* __restrict__ in, float* __restrict__ out, int R, int C) {
    __shared__ float tile[32][33];
    const int tx = threadIdx.x & 31, ty = threadIdx.x >> 5;
    const int c = blockIdx.x * 32 + tx;
#pragma unroll
    for (int k = 0; k < 4; ++k)
        tile[ty + k * 8][tx] = in[(size_t)(blockIdx.y * 32 + ty + k * 8) * C + c];
    __syncthreads();
#pragma unroll
    for (int k = 0; k < 4; ++k)
        out[(size_t)(blockIdx.x * 32 + ty + k * 8) * R + blockIdx.y * 32 + tx] =
            tile[tx][ty + k * 8];
}

// zero h ping-pong buffer 0 (tag 0, value 0.0f == all-zero slot)
__global__ void k_init(u64* hbuf) {
    int i = blockIdx.x * 256 + threadIdx.x;
    if (i < N_DIM) hbuf[i] = 0ull;
}

// ---------------------------------------------------------------------------
// gx = (bf16)x @ Wx + b : A [8192][2048] fp32 row-major (converted inline),
// B [6144][2048] bf16 (Wx^T), C [8192][6144] GXT. 128x128 tile, BK=32,
// 4 waves 2x2.
template <typename GXT>
__global__ __launch_bounds__(256) void k_gemm(const float* __restrict__ A,
                                              const u16* __restrict__ B,
                                              const float* __restrict__ bias,
                                              GXT* __restrict__ C) {
    __shared__ u16 As[128 * 32];
    __shared__ u16 Bs[128 * 32];
    const int tid = threadIdx.x, lane = tid & 63, wave = tid >> 6;
    const int m0 = blockIdx.y * 128, n0 = blockIdx.x * 128;
    const int wm = (wave >> 1) * 64, wn = (wave & 1) * 64;
    const int row0 = tid >> 2, ko0 = (tid & 3) * 8;

    f32x4 acc[4][4] = {};

    for (int k0 = 0; k0 < N_DIM; k0 += 32) {
        const float* ap0 = A + (size_t)(m0 + row0) * N_DIM + k0 + ko0;
        const float* ap1 = A + (size_t)(m0 + 64 + row0) * N_DIM + k0 + ko0;
        float4 a0l = *(const float4*)(ap0), a0h = *(const float4*)(ap0 + 4);
        float4 a1l = *(const float4*)(ap1), a1h = *(const float4*)(ap1 + 4);
        bf16x8 a0, a1;
        a0[0] = (short)f2bf(a0l.x); a0[1] = (short)f2bf(a0l.y);
        a0[2] = (short)f2bf(a0l.z); a0[3] = (short)f2bf(a0l.w);
        a0[4] = (short)f2bf(a0h.x); a0[5] = (short)f2bf(a0h.y);
        a0[6] = (short)f2bf(a0h.z); a0[7] = (short)f2bf(a0h.w);
        a1[0] = (short)f2bf(a1l.x); a1[1] = (short)f2bf(a1l.y);
        a1[2] = (short)f2bf(a1l.z); a1[3] = (short)f2bf(a1l.w);
        a1[4] = (short)f2bf(a1h.x); a1[5] = (short)f2bf(a1h.y);
        a1[6] = (short)f2bf(a1h.z); a1[7] = (short)f2bf(a1h.w);
        bf16x8 b0 = *(const bf16x8*)(B + (size_t)(n0 + row0) * N_DIM + k0 + ko0);
        bf16x8 b1 = *(const bf16x8*)(B + (size_t)(n0 + 64 + row0) * N_DIM + k0 + ko0);
        __syncthreads();
        *(bf16x8*)(As + row0 * 32 + ko0)        = a0;
        *(bf16x8*)(As + (64 + row0) * 32 + ko0) = a1;
        *(bf16x8*)(Bs + row0 * 32 + ko0)        = b0;
        *(bf16x8*)(Bs + (64 + row0) * 32 + ko0) = b1;
        __syncthreads();

        bf16x8 af[4], bfr[4];
#pragma unroll
        for (int mt = 0; mt < 4; ++mt)
            af[mt] = *(const bf16x8*)(As + (wm + mt * 16 + (lane & 15)) * 32 + (lane >> 4) * 8);
#pragma unroll
        for (int nt = 0; nt < 4; ++nt)
            bfr[nt] = *(const bf16x8*)(Bs + (wn + nt * 16 + (lane & 15)) * 32 + (lane >> 4) * 8);
#pragma unroll
        for (int mt = 0; mt < 4; ++mt)
#pragma unroll
            for (int nt = 0; nt < 4; ++nt)
                acc[mt][nt] = __builtin_amdgcn_mfma_f32_16x16x32_bf16(af[mt], bfr[nt],
                                                                      acc[mt][nt], 0, 0, 0);
    }

#pragma unroll
    for (int mt = 0; mt < 4; ++mt)
#pragma unroll
        for (int nt = 0; nt < 4; ++nt) {
            const int col = n0 + wn + nt * 16 + (lane & 15);
            const float bv = bias[col];
#pragma unroll
            for (int r = 0; r < 4; ++r) {
                const int rowm = m0 + wm + mt * 16 + (lane >> 4) * 4 + r;
                const float v = acc[mt][nt][r] + bv;
                if constexpr (sizeof(GXT) == 2)
                    ((u16*)C)[(size_t)rowm * N3 + col] = f2bf(v);
                else
                    ((float*)C)[(size_t)rowm * N3 + col] = v;
            }
        }
}

// ---------------------------------------------------------------------------
// Persistent GRU scan, round 3. 256 blocks x 256 threads (cooperative).
// Slot layout: slot[j*256 + g] holds h-col g*8+j, tagged (step<<32)|fp32bits.
// Thread tid polls slots {tid + 256*i} = cols [tid*8, tid*8+8) -> h arrives
// directly in the registers that consume it (no LDS round-trip, no bank
// conflicts). 24 partials/thread -> 64-lane butterfly -> red[96] -> gates.
// Timed poll backoff: each wave EMA-tracks its step period via s_memrealtime
// (100 MHz) and sleeps until the last quarter before polling, cutting IC
// hot-spot traffic ~3-4x. h_old carried in gate-thread register.
template <typename GXT>
__global__ __launch_bounds__(256, 1) void k_scan(const GXT* __restrict__ gx,
                                                 const float* __restrict__ wht,  // [6144][2048]
                                                 float* __restrict__ out,
                                                 u64* __restrict__ hbuf) {       // [2][2048]
    __shared__ float red[96];
    const int tid = threadIdx.x, lane = tid & 63, wave = tid >> 6;
    const int g = blockIdx.x;

    // wreg[r][i] = Wh^T[C(r)][tid*8+i], contiguous f32x4 gather.
    // C(r) = (r>>3)*2048 + g*8 + (r&7); rows 0..7=z, 8..15=r, 16..23=n.
    float wreg[24][8];
#pragma unroll
    for (int r = 0; r < 24; ++r) {
        const size_t Cb = ((size_t)((r >> 3) * N_DIM + g * 8 + (r & 7))) * N_DIM + tid * 8;
        f32x4 w0 = *(const f32x4*)(wht + Cb);
        f32x4 w1 = *(const f32x4*)(wht + Cb + 4);
#pragma unroll
        for (int j = 0; j < 4; ++j) { wreg[r][j] = w0[j]; wreg[r][4 + j] = w1[j]; }
    }

    float hprev = 0.f;
    u64 t_last = __builtin_amdgcn_s_memrealtime();
    unsigned period = 0;   // EMA of step period, 10ns ticks

    for (int t = 0; t < M_SEQ; ++t) {
        u64* cur = hbuf + (size_t)(t & 1) * N_DIM;
        u64* nxt = hbuf + (size_t)((t + 1) & 1) * N_DIM;
        const unsigned expect = (unsigned)t;

        // Prefetch gate inputs (independent of h; latency hides under wait).
        float xz = 0.f, xr = 0.f, xn = 0.f;
        if (tid < 8) {
            const GXT* gp = gx + (size_t)t * N3 + g * 8 + tid;
            if constexpr (sizeof(GXT) == 2) {
                xz = bf2f(((const u16*)gp)[0]);
                xr = bf2f(((const u16*)gp)[N_DIM]);
                xn = bf2f(((const u16*)gp)[2 * N_DIM]);
            } else {
                xz = ((const float*)gp)[0];
                xr = ((const float*)gp)[N_DIM];
                xn = ((const float*)gp)[2 * N_DIM];
            }
        }

        // Timed backoff: sleep until the last quarter of the expected period.
        if (period) {
            const u64 target = t_last + period - (period >> 2);
            while ((long long)(target - __builtin_amdgcn_s_memrealtime()) > 0)
                __builtin_amdgcn_s_sleep(2);
        }

        // Poll own 8 slots (coalesced: instruction i covers slots [256i,256i+256)).
        u64 v[8];
        for (;;) {
#pragma unroll
            for (int i = 0; i < 8; ++i)
                v[i] = __hip_atomic_load(cur + tid + (i << 8), __ATOMIC_RELAXED,
                                         __HIP_MEMORY_SCOPE_AGENT);
            bool ok = true;
#pragma unroll
            for (int i = 0; i < 8; ++i) ok &= ((unsigned)(v[i] >> 32) == expect);
            if (ok) break;
            __builtin_amdgcn_s_sleep(1);
        }
        {
            const u64 now = __builtin_amdgcn_s_memrealtime();
            const unsigned delta = (unsigned)(now - t_last);
            t_last = now;
            if (delta < 8192u)   // ignore hiccups > ~82 us
                period = period - (period >> 3) + (delta >> 3);
        }

        // 24 rows x 8 local h-cols, all in registers.
        float acc[24];
#pragma unroll
        for (int r = 0; r < 24; ++r) acc[r] = 0.f;
#pragma unroll
        for (int i = 0; i < 8; ++i) {
            const float hv = __builtin_bit_cast(float, (unsigned)(v[i] & 0xffffffffu));
#pragma unroll
            for (int r = 0; r < 24; ++r) acc[r] += wreg[r][i] * hv;
        }

        // Butterfly reduce each row across the wave; lane 0 -> red.
#pragma unroll
        for (int r = 0; r < 24; ++r) {
            float a = acc[r];
#pragma unroll
            for (int off = 32; off; off >>= 1) a += __shfl_xor(a, off, 64);
            if (lane == 0) red[wave * 24 + r] = a;
        }
        __syncthreads();

        // Gates + publish (wave 0, lanes 0..7). h_old lives in hprev register.
        if (tid < 8) {
            const float hz = red[tid]      + red[24 + tid] + red[48 + tid] + red[72 + tid];
            const float hr = red[8 + tid]  + red[32 + tid] + red[56 + tid] + red[80 + tid];
            const float hn = red[16 + tid] + red[40 + tid] + red[64 + tid] + red[88 + tid];
            const float z = 1.f / (1.f + __expf(-(xz + hz)));
            const float r = 1.f / (1.f + __expf(-(xr + hr)));
            const float a2 = xn + r * hn;
            const float cand = 1.f - 2.f / (__expf(2.f * a2) + 1.f);  // tanh(a2)
            const float hnew = (1.f - z) * hprev + z * cand;
            hprev = hnew;
            out[(size_t)t * N_DIM + g * 8 + tid] = hnew;
            const u64 slot = ((u64)(unsigned)(t + 1) << 32) |
                             (u64)__builtin_bit_cast(unsigned, hnew);
            __hip_atomic_store(nxt + tid * 256 + g, slot, __ATOMIC_RELAXED,
                               __HIP_MEMORY_SCOPE_AGENT);
        }
        __syncthreads();   // red[] reuse safety next step
    }
}

// ---------------------------------------------------------------------------
extern "C" void kernel_launch(void* const* d_in, const int* in_sizes, int n_in,
                              void* d_out, int out_size, void* d_ws, size_t ws_size,
                              hipStream_t stream) {
    const float* x  = (const float*)d_in[0];
    const float* Wx = (const float*)d_in[1];
    const float* Wh = (const float*)d_in[2];
    const float* b  = (const float*)d_in[3];
    float* out = (float*)d_out;

    char* ws = (char*)d_ws;
    size_t off = 0;
    auto alloc = [&](size_t bytes) -> char* {
        char* p = ws + off;
        off += (bytes + 255) & ~(size_t)255;
        return p;
    };

    u16*   wxt  = (u16*)  alloc((size_t)N3 * N_DIM * sizeof(u16));
    float* wht  = (float*)alloc((size_t)N3 * N_DIM * sizeof(float));
    u64*   hbuf = (u64*)  alloc((size_t)2 * N_DIM * sizeof(u64));

    const bool gx_f32 = ws_size >= (size_t)290 * 1024 * 1024;

    k_init<<<8, 256, 0, stream>>>(hbuf);
    k_tr_bf16<<<dim3(N3 / 32, N_DIM / 32), 256, 0, stream>>>(Wx, wxt, N_DIM, N3);
    k_tr_f32 <<<dim3(N3 / 32, N_DIM / 32), 256, 0, stream>>>(Wh, wht, N_DIM, N3);

    if (gx_f32) {
        float* gx = (float*)alloc((size_t)M_SEQ * N3 * sizeof(float));
        k_gemm<float><<<dim3(N3 / 128, M_SEQ / 128), 256, 0, stream>>>(x, wxt, b, gx);
        void* args[] = {(void*)&gx, (void*)&wht, (void*)&out, (void*)&hbuf};
        hipError_t e = hipLaunchCooperativeKernel((const void*)k_scan<float>, dim3(256),
                                                  dim3(256), args, 0, stream);
        if (e != hipSuccess)
            k_scan<float><<<256, 256, 0, stream>>>(gx, wht, out, hbuf);
    } else {
        u16* gx = (u16*)alloc((size_t)M_SEQ * N3 * sizeof(u16));
        k_gemm<u16><<<dim3(N3 / 128, M_SEQ / 128), 256, 0, stream>>>(x, wxt, b, gx);
        void* args[] = {(void*)&gx, (void*)&wht, (void*)&out, (void*)&hbuf};
        hipError_t e = hipLaunchCooperativeKernel((const void*)k_scan<u16>, dim3(256),
                                                  dim3(256), args, 0, stream);
        if (e != hipSuccess)
            k_scan<u16><<<256, 256, 0, stream>>>(gx, wht, out, hbuf);
    }
}

// Round 4
// 64727.417 us; speedup vs baseline: 1.0005x; 1.0005x over previous
//
#include <hip/hip_runtime.h>
#include <stdint.h>

#define M_SEQ 8192
#define N_DIM 2048
#define N3    (3 * N_DIM)   // 6144

typedef short bf16x8 __attribute__((ext_vector_type(8)));   // 8 bf16 in 4 VGPRs
typedef float f32x4  __attribute__((ext_vector_type(4)));
typedef unsigned short u16;
typedef unsigned long long u64;

// fp32 -> bf16, round-to-nearest-even
__device__ __forceinline__ u16 f2bf(float f) {
    unsigned int u = __builtin_bit_cast(unsigned int, f);
    u = (u + 0x7fffu + ((u >> 16) & 1u)) >> 16;
    return (u16)u;
}
__device__ __forceinline__ float bf2f(u16 v) {
    return __builtin_bit_cast(float, (unsigned int)v << 16);
}

// ---------------------------------------------------------------------------
// in [R][C] fp32 -> out [C][R] bf16  (tiled transpose)
__global__ void k_tr_bf16(const float* __restrict__ in, u16* __restrict__ out, int R, int C) {
    __shared__ float tile[32][33];
    const int tx = threadIdx.x & 31, ty = threadIdx.x >> 5;
    const int c = blockIdx.x * 32 + tx;
#pragma unroll
    for (int k = 0; k < 4; ++k)
        tile[ty + k * 8][tx] = in[(size_t)(blockIdx.y * 32 + ty + k * 8) * C + c];
    __syncthreads();
#pragma unroll
    for (int k = 0; k < 4; ++k)
        out[(size_t)(blockIdx.x * 32 + ty + k * 8) * R + blockIdx.y * 32 + tx] =
            f2bf(tile[tx][ty + k * 8]);
}

// in [R][C] fp32 -> out [C][R] fp32
__global__ void k_tr_f32(const float* __restrict__ in, float* __restrict__ out, int R, int C) {
    __shared__ float tile[32][33];
    const int tx = threadIdx.x & 31, ty = threadIdx.x >> 5;
    const int c = blockIdx.x * 32 + tx;
#pragma unroll
    for (int k = 0; k < 4; ++k)
        tile[ty + k * 8][tx] = in[(size_t)(blockIdx.y * 32 + ty + k * 8) * C + c];
    __syncthreads();
#pragma unroll
    for (int k = 0; k < 4; ++k)
        out[(size_t)(blockIdx.x * 32 + ty + k * 8) * R + blockIdx.y * 32 + tx] =
            tile[tx][ty + k * 8];
}

// zero h ping-pong buffer 0 (tag 0, value 0.0f == all-zero slot)
__global__ void k_init(u64* hbuf) {
    int i = blockIdx.x * 256 + threadIdx.x;
    if (i < N_DIM) hbuf[i] = 0ull;
}

// ---------------------------------------------------------------------------
// gx = (bf16)x @ Wx + b : A [8192][2048] fp32 row-major (converted inline),
// B [6144][2048] bf16 (Wx^T), C [8192][6144] GXT. 128x128 tile, BK=32,
// 4 waves 2x2.
template <typename GXT>
__global__ __launch_bounds__(256) void k_gemm(const float* __restrict__ A,
                                              const u16* __restrict__ B,
                                              const float* __restrict__ bias,
                                              GXT* __restrict__ C) {
    __shared__ u16 As[128 * 32];
    __shared__ u16 Bs[128 * 32];
    const int tid = threadIdx.x, lane = tid & 63, wave = tid >> 6;
    const int m0 = blockIdx.y * 128, n0 = blockIdx.x * 128;
    const int wm = (wave >> 1) * 64, wn = (wave & 1) * 64;
    const int row0 = tid >> 2, ko0 = (tid & 3) * 8;

    f32x4 acc[4][4] = {};

    for (int k0 = 0; k0 < N_DIM; k0 += 32) {
        const float* ap0 = A + (size_t)(m0 + row0) * N_DIM + k0 + ko0;
        const float* ap1 = A + (size_t)(m0 + 64 + row0) * N_DIM + k0 + ko0;
        float4 a0l = *(const float4*)(ap0), a0h = *(const float4*)(ap0 + 4);
        float4 a1l = *(const float4*)(ap1), a1h = *(const float4*)(ap1 + 4);
        bf16x8 a0, a1;
        a0[0] = (short)f2bf(a0l.x); a0[1] = (short)f2bf(a0l.y);
        a0[2] = (short)f2bf(a0l.z); a0[3] = (short)f2bf(a0l.w);
        a0[4] = (short)f2bf(a0h.x); a0[5] = (short)f2bf(a0h.y);
        a0[6] = (short)f2bf(a0h.z); a0[7] = (short)f2bf(a0h.w);
        a1[0] = (short)f2bf(a1l.x); a1[1] = (short)f2bf(a1l.y);
        a1[2] = (short)f2bf(a1l.z); a1[3] = (short)f2bf(a1l.w);
        a1[4] = (short)f2bf(a1h.x); a1[5] = (short)f2bf(a1h.y);
        a1[6] = (short)f2bf(a1h.z); a1[7] = (short)f2bf(a1h.w);
        bf16x8 b0 = *(const bf16x8*)(B + (size_t)(n0 + row0) * N_DIM + k0 + ko0);
        bf16x8 b1 = *(const bf16x8*)(B + (size_t)(n0 + 64 + row0) * N_DIM + k0 + ko0);
        __syncthreads();
        *(bf16x8*)(As + row0 * 32 + ko0)        = a0;
        *(bf16x8*)(As + (64 + row0) * 32 + ko0) = a1;
        *(bf16x8*)(Bs + row0 * 32 + ko0)        = b0;
        *(bf16x8*)(Bs + (64 + row0) * 32 + ko0) = b1;
        __syncthreads();

        bf16x8 af[4], bfr[4];
#pragma unroll
        for (int mt = 0; mt < 4; ++mt)
            af[mt] = *(const bf16x8*)(As + (wm + mt * 16 + (lane & 15)) * 32 + (lane >> 4) * 8);
#pragma unroll
        for (int nt = 0; nt < 4; ++nt)
            bfr[nt] = *(const bf16x8*)(Bs + (wn + nt * 16 + (lane & 15)) * 32 + (lane >> 4) * 8);
#pragma unroll
        for (int mt = 0; mt < 4; ++mt)
#pragma unroll
            for (int nt = 0; nt < 4; ++nt)
                acc[mt][nt] = __builtin_amdgcn_mfma_f32_16x16x32_bf16(af[mt], bfr[nt],
                                                                      acc[mt][nt], 0, 0, 0);
    }

#pragma unroll
    for (int mt = 0; mt < 4; ++mt)
#pragma unroll
        for (int nt = 0; nt < 4; ++nt) {
            const int col = n0 + wn + nt * 16 + (lane & 15);
            const float bv = bias[col];
#pragma unroll
            for (int r = 0; r < 4; ++r) {
                const int rowm = m0 + wm + mt * 16 + (lane >> 4) * 4 + r;
                const float v = acc[mt][nt][r] + bv;
                if constexpr (sizeof(GXT) == 2)
                    ((u16*)C)[(size_t)rowm * N3 + col] = f2bf(v);
                else
                    ((float*)C)[(size_t)rowm * N3 + col] = v;
            }
        }
}

// ---------------------------------------------------------------------------
// Persistent GRU scan, round 4. 256 blocks x 256 threads (cooperative).
// Slot layout: slot[i] holds h-col i, tagged (step<<32)|fp32bits. Block g
// publishes cols [g*8, g*8+8) -> ONE 64B line per block. Thread tid consumes
// cols [tid*8, tid*8+8) = slots tid*8..tid*8+7 -> h lands directly in the
// consuming registers (no LDS round-trip).
// Two-phase poll: while waiting, poll only the sentinel slot tid*8 (8x less
// coherence-point traffic); once it matches, burst-read all 8 and verify
// every tag (re-read laggards). Fixed short s_sleep — NO adaptive backoff
// (round 3's EMA self-inflated to period = 4x poll RT; see post-mortem).
template <typename GXT>
__global__ __launch_bounds__(256, 1) void k_scan(const GXT* __restrict__ gx,
                                                 const float* __restrict__ wht,  // [6144][2048]
                                                 float* __restrict__ out,
                                                 u64* __restrict__ hbuf) {       // [2][2048]
    __shared__ float red[96];
    const int tid = threadIdx.x, lane = tid & 63, wave = tid >> 6;
    const int g = blockIdx.x;

    // wreg[r][i] = Wh^T[C(r)][tid*8+i], contiguous f32x4 gather.
    // C(r) = (r>>3)*2048 + g*8 + (r&7); rows 0..7=z, 8..15=r, 16..23=n.
    float wreg[24][8];
#pragma unroll
    for (int r = 0; r < 24; ++r) {
        const size_t Cb = ((size_t)((r >> 3) * N_DIM + g * 8 + (r & 7))) * N_DIM + tid * 8;
        f32x4 w0 = *(const f32x4*)(wht + Cb);
        f32x4 w1 = *(const f32x4*)(wht + Cb + 4);
#pragma unroll
        for (int j = 0; j < 4; ++j) { wreg[r][j] = w0[j]; wreg[r][4 + j] = w1[j]; }
    }

    float hprev = 0.f;

    for (int t = 0; t < M_SEQ; ++t) {
        u64* cur = hbuf + (size_t)(t & 1) * N_DIM;
        u64* nxt = hbuf + (size_t)((t + 1) & 1) * N_DIM;
        const unsigned expect = (unsigned)t;

        // Prefetch gate inputs (independent of h; latency hides under wait).
        float xz = 0.f, xr = 0.f, xn = 0.f;
        if (tid < 8) {
            const GXT* gp = gx + (size_t)t * N3 + g * 8 + tid;
            if constexpr (sizeof(GXT) == 2) {
                xz = bf2f(((const u16*)gp)[0]);
                xr = bf2f(((const u16*)gp)[N_DIM]);
                xn = bf2f(((const u16*)gp)[2 * N_DIM]);
            } else {
                xz = ((const float*)gp)[0];
                xr = ((const float*)gp)[N_DIM];
                xn = ((const float*)gp)[2 * N_DIM];
            }
        }

        // Phase A: sentinel poll — one slot per thread.
        for (;;) {
            const u64 s = __hip_atomic_load(cur + tid * 8, __ATOMIC_RELAXED,
                                            __HIP_MEMORY_SCOPE_AGENT);
            if ((unsigned)(s >> 32) == expect) break;
            __builtin_amdgcn_s_sleep(2);
        }

        // Phase B: burst-read own 8 slots, verify all tags, re-read laggards.
        u64 v[8];
#pragma unroll
        for (int i = 0; i < 8; ++i)
            v[i] = __hip_atomic_load(cur + tid * 8 + i, __ATOMIC_RELAXED,
                                     __HIP_MEMORY_SCOPE_AGENT);
        for (;;) {
            bool ok = true;
#pragma unroll
            for (int i = 0; i < 8; ++i) ok &= ((unsigned)(v[i] >> 32) == expect);
            if (ok) break;
            __builtin_amdgcn_s_sleep(1);
#pragma unroll
            for (int i = 0; i < 8; ++i)
                if ((unsigned)(v[i] >> 32) != expect)
                    v[i] = __hip_atomic_load(cur + tid * 8 + i, __ATOMIC_RELAXED,
                                             __HIP_MEMORY_SCOPE_AGENT);
        }

        // 24 rows x 8 local h-cols, all in registers.
        float acc[24];
#pragma unroll
        for (int r = 0; r < 24; ++r) acc[r] = 0.f;
#pragma unroll
        for (int i = 0; i < 8; ++i) {
            const float hv = __builtin_bit_cast(float, (unsigned)(v[i] & 0xffffffffu));
#pragma unroll
            for (int r = 0; r < 24; ++r) acc[r] += wreg[r][i] * hv;
        }

        // Butterfly reduce each row across the wave; lane 0 -> red.
#pragma unroll
        for (int r = 0; r < 24; ++r) {
            float a = acc[r];
#pragma unroll
            for (int off = 32; off; off >>= 1) a += __shfl_xor(a, off, 64);
            if (lane == 0) red[wave * 24 + r] = a;
        }
        __syncthreads();

        // Gates + publish (wave 0, lanes 0..7). h_old lives in hprev register.
        if (tid < 8) {
            const float hz = red[tid]      + red[24 + tid] + red[48 + tid] + red[72 + tid];
            const float hr = red[8 + tid]  + red[32 + tid] + red[56 + tid] + red[80 + tid];
            const float hn = red[16 + tid] + red[40 + tid] + red[64 + tid] + red[88 + tid];
            const float z = 1.f / (1.f + __expf(-(xz + hz)));
            const float r = 1.f / (1.f + __expf(-(xr + hr)));
            const float a2 = xn + r * hn;
            const float cand = 1.f - 2.f / (__expf(2.f * a2) + 1.f);  // tanh(a2)
            const float hnew = (1.f - z) * hprev + z * cand;
            hprev = hnew;
            out[(size_t)t * N_DIM + g * 8 + tid] = hnew;
            const u64 slot = ((u64)(unsigned)(t + 1) << 32) |
                             (u64)__builtin_bit_cast(unsigned, hnew);
            // Contiguous: block g's 8 slots live in ONE 64B line.
            __hip_atomic_store(nxt + g * 8 + tid, slot, __ATOMIC_RELAXED,
                               __HIP_MEMORY_SCOPE_AGENT);
        }
        __syncthreads();   // red[] reuse safety next step
    }
}

// ---------------------------------------------------------------------------
extern "C" void kernel_launch(void* const* d_in, const int* in_sizes, int n_in,
                              void* d_out, int out_size, void* d_ws, size_t ws_size,
                              hipStream_t stream) {
    const float* x  = (const float*)d_in[0];
    const float* Wx = (const float*)d_in[1];
    const float* Wh = (const float*)d_in[2];
    const float* b  = (const float*)d_in[3];
    float* out = (float*)d_out;

    char* ws = (char*)d_ws;
    size_t off = 0;
    auto alloc = [&](size_t bytes) -> char* {
        char* p = ws + off;
        off += (bytes + 255) & ~(size_t)255;
        return p;
    };

    u16*   wxt  = (u16*)  alloc((size_t)N3 * N_DIM * sizeof(u16));
    float* wht  = (float*)alloc((size_t)N3 * N_DIM * sizeof(float));
    u64*   hbuf = (u64*)  alloc((size_t)2 * N_DIM * sizeof(u64));

    const bool gx_f32 = ws_size >= (size_t)290 * 1024 * 1024;

    k_init<<<8, 256, 0, stream>>>(hbuf);
    k_tr_bf16<<<dim3(N3 / 32, N_DIM / 32), 256, 0, stream>>>(Wx, wxt, N_DIM, N3);
    k_tr_f32 <<<dim3(N3 / 32, N_DIM / 32), 256, 0, stream>>>(Wh, wht, N_DIM, N3);

    if (gx_f32) {
        float* gx = (float*)alloc((size_t)M_SEQ * N3 * sizeof(float));
        k_gemm<float><<<dim3(N3 / 128, M_SEQ / 128), 256, 0, stream>>>(x, wxt, b, gx);
        void* args[] = {(void*)&gx, (void*)&wht, (void*)&out, (void*)&hbuf};
        hipError_t e = hipLaunchCooperativeKernel((const void*)k_scan<float>, dim3(256),
                                                  dim3(256), args, 0, stream);
        if (e != hipSuccess)
            k_scan<float><<<256, 256, 0, stream>>>(gx, wht, out, hbuf);
    } else {
        u16* gx = (u16*)alloc((size_t)M_SEQ * N3 * sizeof(u16));
        k_gemm<u16><<<dim3(N3 / 128, M_SEQ / 128), 256, 0, stream>>>(x, wxt, b, gx);
        void* args[] = {(void*)&gx, (void*)&wht, (void*)&out, (void*)&hbuf};
        hipError_t e = hipLaunchCooperativeKernel((const void*)k_scan<u16>, dim3(256),
                                                  dim3(256), args, 0, stream);
        if (e != hipSuccess)
            k_scan<u16><<<256, 256, 0, stream>>>(gx, wht, out, hbuf);
    }
}